// Round 4
// baseline (634.006 us; speedup 1.0000x reference)
//
#include <hip/hip_runtime.h>

#define NN 3070      // nodes
#define NF 128       // in features
#define NO 64        // gcn out features (pre-fold)
#define NH 50        // hidden
#define NC 52        // stored cols after W_ih fold (50 + 2 pad)
#define NE 49120     // edges
#define NB 128       // batch (= rnn seq len)
#define MTOT (NB * NN)   // 392960 rows, = 256 * 1535 exactly
#define GWG3 (7 * NB)    // 896 gather workgroups (batch x f4-pair), %8==0
#define GPX3 (GWG3 / 8)  // 112 per XCD -> 16 whole batches each

// ---------------- init: zero scratch (blocks 0..47) + W_ih fold (blocks 48..79)
// W' = W @ W_ih^T (128x50, pad to 64); b' = b @ W_ih^T + b_ih + b_hh.
__global__ __launch_bounds__(256) void init_kernel(int* __restrict__ zb,
    const float* __restrict__ W, const float* __restrict__ Wih, const float* __restrict__ b,
    const float* __restrict__ bih, const float* __restrict__ bhh,
    float* __restrict__ Wp, float* __restrict__ bp) {
  int blk = blockIdx.x;
  int tid = threadIdx.x;
  if (blk < 48) {
    int i = blk * 256 + tid;
    if (i < 4 * NN) zb[i] = 0;
    return;
  }
  int idx = (blk - 48) * 256 + tid;
  if (idx < 128 * 64) {
    int k = idx >> 6, j = idx & 63;
    float s = 0.f;
    if (j < NH) {
      for (int o = 0; o < NO; ++o) s += W[k * NO + o] * Wih[j * NO + o];
    }
    Wp[k * 64 + j] = s;
  }
  if (idx < NC) {
    float s = 0.f;
    if (idx < NH) {
      for (int o = 0; o < NO; ++o) s += b[o] * Wih[idx * NO + o];
      s += bih[idx] + bhh[idx];
    }
    bp[idx] = s;
  }
}

__global__ __launch_bounds__(256) void mark_kernel(const int* __restrict__ ei, int* __restrict__ mark) {
  int i = blockIdx.x * 256 + threadIdx.x;
  if (i < 2 * NE) mark[ei[i]] = 1;
}

// exclusive prefix scan of n<=3072 ints, single block of 1024 threads, 3 items/thread.
// do_dinv: also compute dinv/selfn from degw (independent work, same dep level).
__global__ __launch_bounds__(1024) void exscan_kernel(const int* __restrict__ in, int* __restrict__ out,
                                                      int n, int write_total, int do_dinv,
                                                      const float* __restrict__ degw,
                                                      float* __restrict__ dinv, float* __restrict__ selfn) {
  __shared__ int part[1024];
  int tid = threadIdx.x;
  int base = tid * 3;
  if (do_dinv) {
#pragma unroll
    for (int u = 0; u < 3; ++u) {
      int nd = base + u;
      if (nd < NN) {
        float dg = degw[nd] + 1.0f;  // + self-loop weight 1
        float di = rsqrtf(dg);       // dg >= 1 always
        dinv[nd] = di;
        selfn[nd] = di * di;         // self-loop message norm
      }
    }
  }
  int v0 = (base + 0 < n) ? in[base + 0] : 0;
  int v1 = (base + 1 < n) ? in[base + 1] : 0;
  int v2 = (base + 2 < n) ? in[base + 2] : 0;
  int s = v0 + v1 + v2;
  part[tid] = s;
  __syncthreads();
  for (int off = 1; off < 1024; off <<= 1) {
    int t = (tid >= off) ? part[tid - off] : 0;
    __syncthreads();
    part[tid] += t;
    __syncthreads();
  }
  int run = part[tid] - s;  // exclusive base of this thread's chunk
  if (base + 0 < n) out[base + 0] = run; run += v0;
  if (base + 1 < n) out[base + 1] = run; run += v1;
  if (base + 2 < n) out[base + 2] = run;
  if (write_total && tid == 1023) out[n] = part[1023];
}

__global__ __launch_bounds__(256) void remap_deg_kernel(const int* __restrict__ ei, const float* __restrict__ ew,
    const int* __restrict__ ranks, int* __restrict__ srcr, int* __restrict__ dstr,
    int* __restrict__ degc, float* __restrict__ degw) {
  int e = blockIdx.x * 256 + threadIdx.x;
  if (e >= NE) return;
  int s = ranks[ei[e]];
  int d = ranks[ei[NE + e]];
  srcr[e] = s;
  dstr[e] = d;
  atomicAdd(&degc[d], 1);
  atomicAdd(&degw[d], ew[e]);
}

// csr edge record: x = src*2 (pre-scaled LDS float4-index), y = float bits of norm
__global__ __launch_bounds__(256) void csr_fill_kernel(const float* __restrict__ ew, const int* __restrict__ srcr,
    const int* __restrict__ dstr, const int* __restrict__ rowptr, int* __restrict__ cursor,
    const float* __restrict__ dinv, int2* __restrict__ csre) {
  int e = blockIdx.x * 256 + threadIdx.x;
  if (e >= NE) return;
  int d = dstr[e];
  int s = srcr[e];
  int pos = rowptr[d] + atomicAdd(&cursor[d], 1);
  float nrm = dinv[s] * ew[e] * dinv[d];
  csre[pos] = make_int2(2 * s, __float_as_int(nrm));
}

// ---------------- GEMM: xw = A(392960,128) @ Wp(128,64), store cols 0..51 ----
// 256-row tile/block (1535 blocks exact), 256 threads, micro-tile 8x8
// (acc=64 VGPRs, 2.0 LDS-FLOP/byte). K chunked by 32. LDS 45KB -> 3 blocks/CU.
// A-tile stride 36: compute reads (4*rg+k4)%32 conflict-free; staging 2-way (free).
__global__ __launch_bounds__(256, 3) void gemm_kernel(const float* __restrict__ A,
    const float* __restrict__ W, float* __restrict__ out) {
  __shared__ float As[256 * 36];   // 36864 B
  __shared__ float Ws[32 * 64];    // 8192 B
  int tid = threadIdx.x;
  int row0 = blockIdx.x * 256;
  int rg = tid >> 3;        // 0..31 : rows rg + 32*i
  int cg = tid & 7;         // cols cg*8 .. cg*8+7
  int c0 = cg * 8;
  float acc[8][8];
#pragma unroll
  for (int i = 0; i < 8; ++i)
#pragma unroll
    for (int j = 0; j < 8; ++j) acc[i][j] = 0.f;

  for (int kc = 0; kc < 4; ++kc) {
    // stage A chunk: 256 rows x 32 k (8 float4 / thread)
#pragma unroll
    for (int j = 0; j < 8; ++j) {
      int f = tid + 256 * j;        // 0..2047
      int r = f >> 3, kq = f & 7;
      float4 v = *(const float4*)&A[(size_t)(row0 + r) * NF + kc * 32 + kq * 4];
      *(float4*)&As[r * 36 + kq * 4] = v;
    }
    // stage W chunk: 32 k x 64 cols (2 float4 / thread)
#pragma unroll
    for (int j = 0; j < 2; ++j) {
      int f = tid + 256 * j;        // 0..511
      int kk = f >> 4, cq = f & 15;
      *(float4*)&Ws[kk * 64 + cq * 4] = *(const float4*)&W[(size_t)(kc * 32 + kk) * 64 + cq * 4];
    }
    __syncthreads();
#pragma unroll 2
    for (int k4 = 0; k4 < 32; k4 += 4) {
      float4 a[8];
#pragma unroll
      for (int i = 0; i < 8; ++i) a[i] = *(const float4*)&As[(rg + 32 * i) * 36 + k4];
#pragma unroll
      for (int m = 0; m < 4; ++m) {
        float4 w0 = *(const float4*)&Ws[(k4 + m) * 64 + c0];
        float4 w1 = *(const float4*)&Ws[(k4 + m) * 64 + c0 + 4];
#pragma unroll
        for (int i = 0; i < 8; ++i) {
          float av = (m == 0) ? a[i].x : (m == 1) ? a[i].y : (m == 2) ? a[i].z : a[i].w;
          acc[i][0] += av * w0.x; acc[i][1] += av * w0.y;
          acc[i][2] += av * w0.z; acc[i][3] += av * w0.w;
          acc[i][4] += av * w1.x; acc[i][5] += av * w1.y;
          acc[i][6] += av * w1.z; acc[i][7] += av * w1.w;
        }
      }
    }
    __syncthreads();
  }
#pragma unroll
  for (int i = 0; i < 8; ++i) {
    size_t r = row0 + rg + 32 * i;
    if (c0 < NC)                 // cg<=6: cols c0..c0+3 valid (cg==6 -> 48..51)
      *(float4*)&out[r * NC + c0] = make_float4(acc[i][0], acc[i][1], acc[i][2], acc[i][3]);
    if (c0 + 4 < NC)             // cg<=5: cols c0+4..c0+7 valid
      *(float4*)&out[r * NC + c0 + 4] = make_float4(acc[i][4], acc[i][5], acc[i][6], acc[i][7]);
  }
}

// ---------------- GCN aggregation: LDS-staged per-batch gather ----------------
// Block = (batch, f4-pair p): stage the batch's xw columns [2p, 2p+1] for ALL
// 3070 nodes into LDS (98,240 B), then each of 512 threads owns 6 contiguous
// dst nodes and walks its CSR range reading sources from LDS (random 16 B LDS
// reads @ ~52 TB/s aggregate vs the old per-edge L2 round-trips @ <=34.5 TB/s).
// One 8 B int2 per edge amortized over 2 f4 columns; src pre-scaled *2.
// 896 blocks, XCD-decoded so each XCD runs 16 whole batches: outg partial-line
// writes and xw partial-line reads from the 7 sibling blocks merge in one L2.
__global__ __launch_bounds__(512, 1) void gather_kernel(const float4* __restrict__ xw,
    const int* __restrict__ rowptr, const int2* __restrict__ csre,
    const float* __restrict__ selfn, const float* __restrict__ bp, float4* __restrict__ outg) {
  __shared__ float4 xls[2 * NN];   // [node*2 + q], 98,240 B -> 1 block/CU, 8 waves
  int bid = blockIdx.x;
  int xcd = bid & 7;
  int pos = bid >> 3;
  int work = xcd * GPX3 + pos;     // bijective: GWG3 % 8 == 0
  int b = work / 7;                // batch
  int p = work - b * 7;            // f4-pair: covers f4 = 2p, 2p+1 (p==6: f4 12 only)
  int f40 = 2 * p;
  int tid = threadIdx.x;
  const float4* xb = xw + (size_t)b * (NN * 13);
  if (p < 6) {
    for (int i = tid; i < 2 * NN; i += 512)
      xls[i] = xb[(i >> 1) * 13 + f40 + (i & 1)];
  } else {
    for (int i = tid; i < NN; i += 512)
      xls[2 * i] = xb[i * 13 + 12];
  }
  __syncthreads();
  int n0 = tid * 6;                // 512*6 = 3072 >= 3070
  if (n0 >= NN) return;
  int nend = n0 + 6 <= NN ? n0 + 6 : NN;
  const float4* bp4 = (const float4*)bp;
  size_t obase = ((size_t)b * NN) * 13;
  if (p < 6) {
    float4 bb0 = bp4[f40], bb1 = bp4[f40 + 1];
    int e = rowptr[n0];
    for (int n = n0; n < nend; ++n) {
      int e1 = rowptr[n + 1];
      float sn = selfn[n];
      float4 x0 = xls[2 * n], x1 = xls[2 * n + 1];
      float a0 = sn * x0.x, a1 = sn * x0.y, a2 = sn * x0.z, a3 = sn * x0.w;
      float c0 = sn * x1.x, c1 = sn * x1.y, c2 = sn * x1.z, c3 = sn * x1.w;
#pragma unroll 2
      for (; e < e1; ++e) {
        int2 ed = csre[e];
        float w = __int_as_float(ed.y);
        float4 u0 = xls[ed.x];
        float4 u1 = xls[ed.x + 1];
        a0 += w * u0.x; a1 += w * u0.y; a2 += w * u0.z; a3 += w * u0.w;
        c0 += w * u1.x; c1 += w * u1.y; c2 += w * u1.z; c3 += w * u1.w;
      }
      size_t o = obase + (size_t)n * 13 + f40;
      outg[o]     = make_float4(a0 + bb0.x, a1 + bb0.y, a2 + bb0.z, a3 + bb0.w);
      outg[o + 1] = make_float4(c0 + bb1.x, c1 + bb1.y, c2 + bb1.z, c3 + bb1.w);
    }
  } else {
    float4 bb0 = bp4[12];
    int e = rowptr[n0];
    for (int n = n0; n < nend; ++n) {
      int e1 = rowptr[n + 1];
      float sn = selfn[n];
      float4 x0 = xls[2 * n];
      float a0 = sn * x0.x, a1 = sn * x0.y, a2 = sn * x0.z, a3 = sn * x0.w;
#pragma unroll 2
      for (; e < e1; ++e) {
        int2 ed = csre[e];
        float w = __int_as_float(ed.y);
        float4 u0 = xls[ed.x];
        a0 += w * u0.x; a1 += w * u0.y; a2 += w * u0.z; a3 += w * u0.w;
      }
      outg[obase + (size_t)n * 13 + 12] =
          make_float4(a0 + bb0.x, a1 + bb0.y, a2 + bb0.z, a3 + bb0.w);
    }
  }
}

// ---------------- RNN: h = tanh(pre + W_hh h), input term pre-folded --------
// block = 5 nodes x 50 j (250/256 lanes); 128 steps; whh row = 25 float2 regs.
// tanh inlined via __expf + rcp (no libcall -> no forced spills).
// (Exact R1 version — the lgkm-only-barrier variant regressed +6us, reverted.)
__global__ __launch_bounds__(256, 3) void rnn_kernel(const float* __restrict__ pre,
    const float* __restrict__ Whh, const float* __restrict__ h0, float* __restrict__ out) {
  __shared__ float hs[6 * 52];   // row 5 = scratch for inactive lanes
  int tid = threadIdx.x;
  int n0 = blockIdx.x * 5;
  int nl = tid / 50;
  int j = tid - nl * 50;
  bool active = tid < 250;
  int jj = active ? j : 0;
  float2 whh2[25];
  const float2* whhp = (const float2*)(Whh + jj * NH);
#pragma unroll
  for (int q = 0; q < 25; ++q) whh2[q] = whhp[q];
  if (tid < 6 * 52) hs[tid] = 0.f;
  if (tid + 256 < 6 * 52) hs[tid + 256] = 0.f;
  __syncthreads();
  if (active) hs[nl * 52 + j] = h0[n0 * 50 + tid];
  const size_t NPRE = (size_t)NN * NC;
  const size_t NOUT = (size_t)NN * NH;
  int nn = active ? (n0 + nl) : n0;
  const float* prep = pre + (size_t)nn * NC + jj;
  float xpre = prep[0];
  __syncthreads();
  for (int t = 0; t < NB; ++t) {
    float a0 = xpre, a1 = 0.f, a2 = 0.f, a3 = 0.f;
    if (t + 1 < NB) xpre = prep[(size_t)(t + 1) * NPRE];  // prefetch next step
    const float4* hr = (const float4*)&hs[nl * 52];       // 208B-aligned
#pragma unroll
    for (int q = 0; q < 12; q += 4) {
      float4 h0v = hr[q], h1v = hr[q + 1], h2v = hr[q + 2], h3v = hr[q + 3];
      a0 += h0v.x * whh2[2*q].x   + h0v.y * whh2[2*q].y   + h0v.z * whh2[2*q+1].x + h0v.w * whh2[2*q+1].y;
      a1 += h1v.x * whh2[2*q+2].x + h1v.y * whh2[2*q+2].y + h1v.z * whh2[2*q+3].x + h1v.w * whh2[2*q+3].y;
      a2 += h2v.x * whh2[2*q+4].x + h2v.y * whh2[2*q+4].y + h2v.z * whh2[2*q+5].x + h2v.w * whh2[2*q+5].y;
      a3 += h3v.x * whh2[2*q+6].x + h3v.y * whh2[2*q+6].y + h3v.z * whh2[2*q+7].x + h3v.w * whh2[2*q+7].y;
    }
    {
      float2 ht = *(const float2*)&hs[nl * 52 + 48];
      a0 += ht.x * whh2[24].x + ht.y * whh2[24].y;
    }
    float v = (a0 + a1) + (a2 + a3);
    float e = __expf(-2.f * fabsf(v));
    float r = (1.f - e) * __builtin_amdgcn_rcpf(1.f + e);
    float hnew = (v < 0.f) ? -r : r;
    __syncthreads();  // all hs reads done
    if (active) {
      hs[nl * 52 + j] = hnew;
      out[(size_t)t * NOUT + n0 * 50 + tid] = hnew;  // contiguous 250 floats/block
    }
    __syncthreads();  // hs writes visible
  }
}

// ---------------- host ----------------

extern "C" void kernel_launch(void* const* d_in, const int* in_sizes, int n_in,
                              void* d_out, int out_size, void* d_ws, size_t ws_size,
                              hipStream_t stream) {
  const float* x_in = (const float*)d_in[0];
  const int* ei     = (const int*)d_in[1];
  const float* ew   = (const float*)d_in[2];
  const float* W    = (const float*)d_in[3];
  const float* bias = (const float*)d_in[4];
  const float* Wih  = (const float*)d_in[5];
  const float* Whh  = (const float*)d_in[6];
  const float* bih  = (const float*)d_in[7];
  const float* bhh  = (const float*)d_in[8];
  const float* h0   = (const float*)d_in[9];
  float* out = (float*)d_out;

  char* ws = (char*)d_ws;
  size_t off = 0;
  auto alloc = [&](size_t bytes) {
    size_t o = off;
    off += (bytes + 255) & ~(size_t)255;
    return o;
  };
  float* xw    = (float*)(ws + alloc((size_t)MTOT * NC * 4));         // 81.7 MB
  float* gcn   = (float*)(ws + alloc((size_t)MTOT * NC * 4));         // 81.7 MB
  int*   zb    = (int*)(ws + alloc((size_t)4 * NN * 4));              // zeroed each call
  int* mark = zb;
  int* degc = zb + NN;
  float* degw = (float*)(zb + 2 * NN);
  int* cursor = zb + 3 * NN;
  int*   ranks  = (int*)(ws + alloc(NN * 4));
  int*   srcr   = (int*)(ws + alloc(NE * 4));
  int*   dstr   = (int*)(ws + alloc(NE * 4));
  float* dinv   = (float*)(ws + alloc(NN * 4));
  float* selfn  = (float*)(ws + alloc(NN * 4));
  int*   rowptr = (int*)(ws + alloc((NN + 1) * 4));
  int2*  csre   = (int2*)(ws + alloc((size_t)NE * 8));
  float* Wp     = (float*)(ws + alloc(128 * 64 * 4));
  float* bp     = (float*)(ws + alloc(NC * 4));

  init_kernel<<<80, 256, 0, stream>>>(zb, W, Wih, bias, bih, bhh, Wp, bp);
  mark_kernel<<<(2 * NE + 255) / 256, 256, 0, stream>>>(ei, mark);
  exscan_kernel<<<1, 1024, 0, stream>>>(mark, ranks, NN, 0, 0, degw, dinv, selfn);
  remap_deg_kernel<<<(NE + 255) / 256, 256, 0, stream>>>(ei, ew, ranks, srcr, dstr, degc, degw);
  exscan_kernel<<<1, 1024, 0, stream>>>(degc, rowptr, NN, 1, 1, degw, dinv, selfn);
  csr_fill_kernel<<<(NE + 255) / 256, 256, 0, stream>>>(ew, srcr, dstr, rowptr, cursor, dinv, csre);

  gemm_kernel<<<MTOT / 256, 256, 0, stream>>>(x_in, Wp, xw);
  gather_kernel<<<GWG3, 512, 0, stream>>>(
      (const float4*)xw, rowptr, csre, selfn, bp, (float4*)gcn);
  rnn_kernel<<<(NN + 4) / 5, 256, 0, stream>>>(gcn, Whh, h0, out);
}

// Round 5
// 533.927 us; speedup vs baseline: 1.1874x; 1.1874x over previous
//
#include <hip/hip_runtime.h>

#define NN 3070      // nodes
#define NF 128       // in features
#define NO 64        // gcn out features (pre-fold)
#define NH 50        // hidden
#define NC 52        // stored cols after W_ih fold (50 + 2 pad)
#define NE 49120     // edges
#define NB 128       // batch (= rnn seq len)
#define MTOT (NB * NN)   // 392960 rows, = 256 * 1535 exactly
#define GCAP 1024        // staged edges per 16-node gather block
#define NBLK 192         // node blocks of 16 (192*16 = 3072 >= 3070)
#define GWG (NBLK * NB)  // 24576 gather workgroups, divisible by 8 XCDs
#define GPX (GWG / 8)    // 3072 workgroups per XCD -> 16 whole batches each

// ---------------- init: zero scratch (blocks 0..47) + W_ih fold (blocks 48..79)
// W' = W @ W_ih^T (128x50, pad to 64); b' = b @ W_ih^T + b_ih + b_hh.
__global__ __launch_bounds__(256) void init_kernel(int* __restrict__ zb,
    const float* __restrict__ W, const float* __restrict__ Wih, const float* __restrict__ b,
    const float* __restrict__ bih, const float* __restrict__ bhh,
    float* __restrict__ Wp, float* __restrict__ bp) {
  int blk = blockIdx.x;
  int tid = threadIdx.x;
  if (blk < 48) {
    int i = blk * 256 + tid;
    if (i < 4 * NN) zb[i] = 0;
    return;
  }
  int idx = (blk - 48) * 256 + tid;
  if (idx < 128 * 64) {
    int k = idx >> 6, j = idx & 63;
    float s = 0.f;
    if (j < NH) {
      for (int o = 0; o < NO; ++o) s += W[k * NO + o] * Wih[j * NO + o];
    }
    Wp[k * 64 + j] = s;
  }
  if (idx < NC) {
    float s = 0.f;
    if (idx < NH) {
      for (int o = 0; o < NO; ++o) s += b[o] * Wih[idx * NO + o];
      s += bih[idx] + bhh[idx];
    }
    bp[idx] = s;
  }
}

__global__ __launch_bounds__(256) void mark_kernel(const int* __restrict__ ei, int* __restrict__ mark) {
  int i = blockIdx.x * 256 + threadIdx.x;
  if (i < 2 * NE) mark[ei[i]] = 1;
}

// exclusive prefix scan of n<=3072 ints, single block of 1024 threads, 3 items/thread.
// do_dinv: also compute dinv/selfn from degw (independent work, same dep level).
__global__ __launch_bounds__(1024) void exscan_kernel(const int* __restrict__ in, int* __restrict__ out,
                                                      int n, int write_total, int do_dinv,
                                                      const float* __restrict__ degw,
                                                      float* __restrict__ dinv, float* __restrict__ selfn) {
  __shared__ int part[1024];
  int tid = threadIdx.x;
  int base = tid * 3;
  if (do_dinv) {
#pragma unroll
    for (int u = 0; u < 3; ++u) {
      int nd = base + u;
      if (nd < NN) {
        float dg = degw[nd] + 1.0f;  // + self-loop weight 1
        float di = rsqrtf(dg);       // dg >= 1 always
        dinv[nd] = di;
        selfn[nd] = di * di;         // self-loop message norm
      }
    }
  }
  int v0 = (base + 0 < n) ? in[base + 0] : 0;
  int v1 = (base + 1 < n) ? in[base + 1] : 0;
  int v2 = (base + 2 < n) ? in[base + 2] : 0;
  int s = v0 + v1 + v2;
  part[tid] = s;
  __syncthreads();
  for (int off = 1; off < 1024; off <<= 1) {
    int t = (tid >= off) ? part[tid - off] : 0;
    __syncthreads();
    part[tid] += t;
    __syncthreads();
  }
  int run = part[tid] - s;  // exclusive base of this thread's chunk
  if (base + 0 < n) out[base + 0] = run; run += v0;
  if (base + 1 < n) out[base + 1] = run; run += v1;
  if (base + 2 < n) out[base + 2] = run;
  if (write_total && tid == 1023) out[n] = part[1023];
}

__global__ __launch_bounds__(256) void remap_deg_kernel(const int* __restrict__ ei, const float* __restrict__ ew,
    const int* __restrict__ ranks, int* __restrict__ srcr, int* __restrict__ dstr,
    int* __restrict__ degc, float* __restrict__ degw) {
  int e = blockIdx.x * 256 + threadIdx.x;
  if (e >= NE) return;
  int s = ranks[ei[e]];
  int d = ranks[ei[NE + e]];
  srcr[e] = s;
  dstr[e] = d;
  atomicAdd(&degc[d], 1);
  atomicAdd(&degw[d], ew[e]);
}

__global__ __launch_bounds__(256) void csr_fill_kernel(const float* __restrict__ ew, const int* __restrict__ srcr,
    const int* __restrict__ dstr, const int* __restrict__ rowptr, int* __restrict__ cursor,
    const float* __restrict__ dinv, int* __restrict__ csr_src, float* __restrict__ csr_norm) {
  int e = blockIdx.x * 256 + threadIdx.x;
  if (e >= NE) return;
  int d = dstr[e];
  int s = srcr[e];
  int pos = rowptr[d] + atomicAdd(&cursor[d], 1);
  csr_src[pos] = s;
  csr_norm[pos] = dinv[s] * ew[e] * dinv[d];
}

// ---------------- GEMM: xw = A(392960,128) @ Wp(128,64), store cols 0..51 ----
// 256-row tile/block (1535 blocks exact), 256 threads, micro-tile 8x8
// (acc=64 VGPRs, 2.0 LDS-FLOP/byte). K chunked by 32. LDS 45KB -> 3 blocks/CU.
// A-tile stride 36: compute reads (4*rg+k4)%32 conflict-free; staging 2-way (free).
__global__ __launch_bounds__(256, 3) void gemm_kernel(const float* __restrict__ A,
    const float* __restrict__ W, float* __restrict__ out) {
  __shared__ float As[256 * 36];   // 36864 B
  __shared__ float Ws[32 * 64];    // 8192 B
  int tid = threadIdx.x;
  int row0 = blockIdx.x * 256;
  int rg = tid >> 3;        // 0..31 : rows rg + 32*i
  int cg = tid & 7;         // cols cg*8 .. cg*8+7
  int c0 = cg * 8;
  float acc[8][8];
#pragma unroll
  for (int i = 0; i < 8; ++i)
#pragma unroll
    for (int j = 0; j < 8; ++j) acc[i][j] = 0.f;

  for (int kc = 0; kc < 4; ++kc) {
    // stage A chunk: 256 rows x 32 k (8 float4 / thread)
#pragma unroll
    for (int j = 0; j < 8; ++j) {
      int f = tid + 256 * j;        // 0..2047
      int r = f >> 3, kq = f & 7;
      float4 v = *(const float4*)&A[(size_t)(row0 + r) * NF + kc * 32 + kq * 4];
      *(float4*)&As[r * 36 + kq * 4] = v;
    }
    // stage W chunk: 32 k x 64 cols (2 float4 / thread)
#pragma unroll
    for (int j = 0; j < 2; ++j) {
      int f = tid + 256 * j;        // 0..511
      int kk = f >> 4, cq = f & 15;
      *(float4*)&Ws[kk * 64 + cq * 4] = *(const float4*)&W[(size_t)(kc * 32 + kk) * 64 + cq * 4];
    }
    __syncthreads();
#pragma unroll 2
    for (int k4 = 0; k4 < 32; k4 += 4) {
      float4 a[8];
#pragma unroll
      for (int i = 0; i < 8; ++i) a[i] = *(const float4*)&As[(rg + 32 * i) * 36 + k4];
#pragma unroll
      for (int m = 0; m < 4; ++m) {
        float4 w0 = *(const float4*)&Ws[(k4 + m) * 64 + c0];
        float4 w1 = *(const float4*)&Ws[(k4 + m) * 64 + c0 + 4];
#pragma unroll
        for (int i = 0; i < 8; ++i) {
          float av = (m == 0) ? a[i].x : (m == 1) ? a[i].y : (m == 2) ? a[i].z : a[i].w;
          acc[i][0] += av * w0.x; acc[i][1] += av * w0.y;
          acc[i][2] += av * w0.z; acc[i][3] += av * w0.w;
          acc[i][4] += av * w1.x; acc[i][5] += av * w1.y;
          acc[i][6] += av * w1.z; acc[i][7] += av * w1.w;
        }
      }
    }
    __syncthreads();
  }
#pragma unroll
  for (int i = 0; i < 8; ++i) {
    size_t r = row0 + rg + 32 * i;
    if (c0 < NC)                 // cg<=6: cols c0..c0+3 valid (cg==6 -> 48..51)
      *(float4*)&out[r * NC + c0] = make_float4(acc[i][0], acc[i][1], acc[i][2], acc[i][3]);
    if (c0 + 4 < NC)             // cg<=5: cols c0+4..c0+7 valid
      *(float4*)&out[r * NC + c0 + 4] = make_float4(acc[i][4], acc[i][5], acc[i][6], acc[i][7]);
  }
}

// ---------------- GCN aggregation: atomic-free CSR gather (52-col) ----------
// Block = 16 nodes x 13 float4-feats (f4<13 active of 16). Best measured
// version (R1): 1 batch/block; LDS-staged variant (R4) lost 2x to LDS bank
// conflicts (1.7e7) + 1-block/CU occupancy -> L2 random-line reads win.
// XCD-aware decode: xcd = bid&7, pos = bid>>3 gives each XCD a contiguous
// 3072-work range = 16 whole batches; per-batch 638 KB xw slice stays in one
// XCD's L2 (fetched once from HBM instead of 8x).
__global__ __launch_bounds__(256) void gather_kernel(const float4* __restrict__ xw,
    const int* __restrict__ rowptr, const int* __restrict__ csr_src, const float* __restrict__ csr_norm,
    const float* __restrict__ selfn, const float* __restrict__ bp, float4* __restrict__ outg) {
  __shared__ int s_src[GCAP];
  __shared__ float s_nrm[GCAP];
  int bid = blockIdx.x;
  int xcd = bid & 7;
  int pos = bid >> 3;
  int work = xcd * GPX + pos;        // bijective: GWG % 8 == 0
  int b = work / NBLK;               // batch: 16 consecutive batches per XCD
  int nblk = work - b * NBLK;        // node-block within batch
  int tid = threadIdx.x;
  int f4 = tid & 15, nl = tid >> 4;
  int nb = nblk * 16;
  int nend = nb + 16 < NN ? nb + 16 : NN;
  int be0 = rowptr[nb], be1 = rowptr[nend];
  int cnt = be1 - be0;
  int scnt = cnt < GCAP ? cnt : GCAP;
  for (int i = tid; i < scnt; i += 256) {
    s_src[i] = csr_src[be0 + i];
    s_nrm[i] = csr_norm[be0 + i];
  }
  __syncthreads();
  int n = nb + nl;
  if (n >= NN || f4 >= 13) return;
  const float4* xb = xw + (size_t)b * NN * 13;
  float sn = selfn[n];
  float4 v = xb[n * 13 + f4];
  float ax = v.x * sn, ay = v.y * sn, az = v.z * sn, aw = v.w * sn;
  float bx = 0.f, by = 0.f, bz = 0.f, bw = 0.f;
  int le0 = rowptr[n] - be0, le1 = rowptr[n + 1] - be0;
  int lim = le1 < GCAP ? le1 : GCAP;
  int e = le0;
  for (; e + 1 < lim; e += 2) {
    int s1 = s_src[e], s2 = s_src[e + 1];
    float w1 = s_nrm[e], w2 = s_nrm[e + 1];
    float4 u1 = xb[s1 * 13 + f4];
    float4 u2 = xb[s2 * 13 + f4];
    ax += w1 * u1.x; ay += w1 * u1.y; az += w1 * u1.z; aw += w1 * u1.w;
    bx += w2 * u2.x; by += w2 * u2.y; bz += w2 * u2.z; bw += w2 * u2.w;
  }
  if (e < lim) {
    int s1 = s_src[e];
    float w1 = s_nrm[e];
    float4 u1 = xb[s1 * 13 + f4];
    ax += w1 * u1.x; ay += w1 * u1.y; az += w1 * u1.z; aw += w1 * u1.w;
  }
  for (e = (le0 > GCAP ? le0 : GCAP); e < le1; ++e) {   // overflow tail
    int s1 = csr_src[be0 + e];
    float w1 = csr_norm[be0 + e];
    float4 u1 = xb[s1 * 13 + f4];
    ax += w1 * u1.x; ay += w1 * u1.y; az += w1 * u1.z; aw += w1 * u1.w;
  }
  float4 bb = ((const float4*)bp)[f4];
  float4 o = make_float4(ax + bx + bb.x, ay + by + bb.y, az + bz + bb.z, aw + bw + bb.w);
  outg[((size_t)b * NN + n) * 13 + f4] = o;
}

// ---------------- RNN: h = tanh(pre + W_hh h), input term pre-folded --------
// WAVE-AUTONOMOUS: 1 wave = 1 node (50 of 64 lanes active), h lives in a
// wave-private 64-float LDS row. The per-wave DS pipe is in-order, so step
// t's ds_write is seen by step t+1's broadcast reads with NO barrier and NO
// compiler-emitted vmcnt(0) drain (which __syncthreads forced every step in
// the 5-node/block version, stalling on the out-store + xpre prefetch).
// FMA ordering per lane identical to the previous version -> same rounding.
__global__ __launch_bounds__(256, 3) void rnn_kernel(const float* __restrict__ pre,
    const float* __restrict__ Whh, const float* __restrict__ h0, float* __restrict__ out) {
  __shared__ float hs[4 * 64];   // 4 waves x 64-float row (256 B aligned)
  int tid = threadIdx.x;
  int w = tid >> 6;              // wave -> node slot
  int j = tid & 63;
  int n = blockIdx.x * 4 + w;
  if (n >= NN) return;           // wave-uniform exit; no barriers anywhere
  bool active = j < NH;
  int jj = active ? j : 0;
  float2 whh2[25];
  const float2* whhp = (const float2*)(Whh + jj * NH);
#pragma unroll
  for (int q = 0; q < 25; ++q) whh2[q] = whhp[q];
  hs[w * 64 + j] = active ? h0[(size_t)n * NH + j] : 0.f;
  const size_t NPRE = (size_t)NN * NC;
  const size_t NOUT = (size_t)NN * NH;
  const float* prep = pre + (size_t)n * NC + jj;
  float xpre = prep[0];
  const float4* hr = (const float4*)&hs[w * 64];
  for (int t = 0; t < NB; ++t) {
    float a0 = xpre, a1 = 0.f, a2 = 0.f, a3 = 0.f;
    if (t + 1 < NB) xpre = prep[(size_t)(t + 1) * NPRE];  // prefetch next step
#pragma unroll
    for (int q = 0; q < 12; q += 4) {
      float4 h0v = hr[q], h1v = hr[q + 1], h2v = hr[q + 2], h3v = hr[q + 3];
      a0 += h0v.x * whh2[2*q].x   + h0v.y * whh2[2*q].y   + h0v.z * whh2[2*q+1].x + h0v.w * whh2[2*q+1].y;
      a1 += h1v.x * whh2[2*q+2].x + h1v.y * whh2[2*q+2].y + h1v.z * whh2[2*q+3].x + h1v.w * whh2[2*q+3].y;
      a2 += h2v.x * whh2[2*q+4].x + h2v.y * whh2[2*q+4].y + h2v.z * whh2[2*q+5].x + h2v.w * whh2[2*q+5].y;
      a3 += h3v.x * whh2[2*q+6].x + h3v.y * whh2[2*q+6].y + h3v.z * whh2[2*q+7].x + h3v.w * whh2[2*q+7].y;
    }
    {
      float2 ht = *(const float2*)&hs[w * 64 + 48];
      a0 += ht.x * whh2[24].x + ht.y * whh2[24].y;
    }
    float v = (a0 + a1) + (a2 + a3);
    float e = __expf(-2.f * fabsf(v));
    float r = (1.f - e) * __builtin_amdgcn_rcpf(1.f + e);
    float hnew = (v < 0.f) ? -r : r;
    if (active) {
      hs[w * 64 + j] = hnew;     // in-order DS pipe: visible to next-iter reads
      out[(size_t)t * NOUT + (size_t)n * NH + j] = hnew;  // 200 B/wave contiguous
    }
  }
}

// ---------------- host ----------------

extern "C" void kernel_launch(void* const* d_in, const int* in_sizes, int n_in,
                              void* d_out, int out_size, void* d_ws, size_t ws_size,
                              hipStream_t stream) {
  const float* x_in = (const float*)d_in[0];
  const int* ei     = (const int*)d_in[1];
  const float* ew   = (const float*)d_in[2];
  const float* W    = (const float*)d_in[3];
  const float* bias = (const float*)d_in[4];
  const float* Wih  = (const float*)d_in[5];
  const float* Whh  = (const float*)d_in[6];
  const float* bih  = (const float*)d_in[7];
  const float* bhh  = (const float*)d_in[8];
  const float* h0   = (const float*)d_in[9];
  float* out = (float*)d_out;

  char* ws = (char*)d_ws;
  size_t off = 0;
  auto alloc = [&](size_t bytes) {
    size_t o = off;
    off += (bytes + 255) & ~(size_t)255;
    return o;
  };
  float* xw    = (float*)(ws + alloc((size_t)MTOT * NC * 4));         // 81.7 MB
  float* gcn   = (float*)(ws + alloc((size_t)MTOT * NC * 4));         // 81.7 MB
  int*   zb    = (int*)(ws + alloc((size_t)4 * NN * 4));              // zeroed each call
  int* mark = zb;
  int* degc = zb + NN;
  float* degw = (float*)(zb + 2 * NN);
  int* cursor = zb + 3 * NN;
  int*   ranks  = (int*)(ws + alloc(NN * 4));
  int*   srcr   = (int*)(ws + alloc(NE * 4));
  int*   dstr   = (int*)(ws + alloc(NE * 4));
  float* dinv   = (float*)(ws + alloc(NN * 4));
  float* selfn  = (float*)(ws + alloc(NN * 4));
  int*   rowptr = (int*)(ws + alloc((NN + 1) * 4));
  int*   csrc   = (int*)(ws + alloc(NE * 4));
  float* cnorm  = (float*)(ws + alloc(NE * 4));
  float* Wp     = (float*)(ws + alloc(128 * 64 * 4));
  float* bp     = (float*)(ws + alloc(NC * 4));

  init_kernel<<<80, 256, 0, stream>>>(zb, W, Wih, bias, bih, bhh, Wp, bp);
  mark_kernel<<<(2 * NE + 255) / 256, 256, 0, stream>>>(ei, mark);
  exscan_kernel<<<1, 1024, 0, stream>>>(mark, ranks, NN, 0, 0, degw, dinv, selfn);
  remap_deg_kernel<<<(NE + 255) / 256, 256, 0, stream>>>(ei, ew, ranks, srcr, dstr, degc, degw);
  exscan_kernel<<<1, 1024, 0, stream>>>(degc, rowptr, NN, 1, 1, degw, dinv, selfn);
  csr_fill_kernel<<<(NE + 255) / 256, 256, 0, stream>>>(ew, srcr, dstr, rowptr, cursor, dinv, csrc, cnorm);

  gemm_kernel<<<MTOT / 256, 256, 0, stream>>>(x_in, Wp, xw);
  gather_kernel<<<GWG, 256, 0, stream>>>(
      (const float4*)xw, rowptr, csrc, cnorm, selfn, bp, (float4*)gcn);
  rnn_kernel<<<(NN + 3) / 4, 256, 0, stream>>>(gcn, Whh, h0, out);
}

// Round 8
// 527.369 us; speedup vs baseline: 1.2022x; 1.0124x over previous
//
#include <hip/hip_runtime.h>

#define NN 3070      // nodes
#define NF 128       // in features
#define NO 64        // gcn out features (pre-fold)
#define NH 50        // hidden
#define NC 52        // stored cols after W_ih fold (50 + 2 pad)
#define NE 49120     // edges
#define NB 128       // batch (= rnn seq len)
#define MTOT (NB * NN)   // 392960 rows, = 256 * 1535 exactly
#define GCAP 1024        // staged edges per 16-node gather block
#define NBLK 192         // node blocks of 16 (192*16 = 3072 >= 3070)
#define GWG (NBLK * NB)  // 24576 gather workgroups, divisible by 8 XCDs
#define GPX (GWG / 8)    // 3072 workgroups per XCD -> 16 whole batches each

// NOTE (R6/R7 lesson): hipLaunchCooperativeKernel broke graph capture (R6),
// and the R6/R7-only RNN prefetch-ring rewrite is the remaining suspect for
// the R7 container failure. This file is the EXACT last-passing (R5) source:
// 6 graph-safe preproc micro-launches + R1 gather + wave-autonomous RNN.

// ---------------- init: zero scratch (blocks 0..47) + W_ih fold (blocks 48..79)
// W' = W @ W_ih^T (128x50, pad to 64); b' = b @ W_ih^T + b_ih + b_hh.
__global__ __launch_bounds__(256) void init_kernel(int* __restrict__ zb,
    const float* __restrict__ W, const float* __restrict__ Wih, const float* __restrict__ b,
    const float* __restrict__ bih, const float* __restrict__ bhh,
    float* __restrict__ Wp, float* __restrict__ bp) {
  int blk = blockIdx.x;
  int tid = threadIdx.x;
  if (blk < 48) {
    int i = blk * 256 + tid;
    if (i < 4 * NN) zb[i] = 0;
    return;
  }
  int idx = (blk - 48) * 256 + tid;
  if (idx < 128 * 64) {
    int k = idx >> 6, j = idx & 63;
    float s = 0.f;
    if (j < NH) {
      for (int o = 0; o < NO; ++o) s += W[k * NO + o] * Wih[j * NO + o];
    }
    Wp[k * 64 + j] = s;
  }
  if (idx < NC) {
    float s = 0.f;
    if (idx < NH) {
      for (int o = 0; o < NO; ++o) s += b[o] * Wih[idx * NO + o];
      s += bih[idx] + bhh[idx];
    }
    bp[idx] = s;
  }
}

__global__ __launch_bounds__(256) void mark_kernel(const int* __restrict__ ei, int* __restrict__ mark) {
  int i = blockIdx.x * 256 + threadIdx.x;
  if (i < 2 * NE) mark[ei[i]] = 1;
}

// exclusive prefix scan of n<=3072 ints, single block of 1024 threads, 3 items/thread.
// do_dinv: also compute dinv/selfn from degw (independent work, same dep level).
__global__ __launch_bounds__(1024) void exscan_kernel(const int* __restrict__ in, int* __restrict__ out,
                                                      int n, int write_total, int do_dinv,
                                                      const float* __restrict__ degw,
                                                      float* __restrict__ dinv, float* __restrict__ selfn) {
  __shared__ int part[1024];
  int tid = threadIdx.x;
  int base = tid * 3;
  if (do_dinv) {
#pragma unroll
    for (int u = 0; u < 3; ++u) {
      int nd = base + u;
      if (nd < NN) {
        float dg = degw[nd] + 1.0f;  // + self-loop weight 1
        float di = rsqrtf(dg);       // dg >= 1 always
        dinv[nd] = di;
        selfn[nd] = di * di;         // self-loop message norm
      }
    }
  }
  int v0 = (base + 0 < n) ? in[base + 0] : 0;
  int v1 = (base + 1 < n) ? in[base + 1] : 0;
  int v2 = (base + 2 < n) ? in[base + 2] : 0;
  int s = v0 + v1 + v2;
  part[tid] = s;
  __syncthreads();
  for (int off = 1; off < 1024; off <<= 1) {
    int t = (tid >= off) ? part[tid - off] : 0;
    __syncthreads();
    part[tid] += t;
    __syncthreads();
  }
  int run = part[tid] - s;  // exclusive base of this thread's chunk
  if (base + 0 < n) out[base + 0] = run; run += v0;
  if (base + 1 < n) out[base + 1] = run; run += v1;
  if (base + 2 < n) out[base + 2] = run;
  if (write_total && tid == 1023) out[n] = part[1023];
}

__global__ __launch_bounds__(256) void remap_deg_kernel(const int* __restrict__ ei, const float* __restrict__ ew,
    const int* __restrict__ ranks, int* __restrict__ srcr, int* __restrict__ dstr,
    int* __restrict__ degc, float* __restrict__ degw) {
  int e = blockIdx.x * 256 + threadIdx.x;
  if (e >= NE) return;
  int s = ranks[ei[e]];
  int d = ranks[ei[NE + e]];
  srcr[e] = s;
  dstr[e] = d;
  atomicAdd(&degc[d], 1);
  atomicAdd(&degw[d], ew[e]);
}

__global__ __launch_bounds__(256) void csr_fill_kernel(const float* __restrict__ ew, const int* __restrict__ srcr,
    const int* __restrict__ dstr, const int* __restrict__ rowptr, int* __restrict__ cursor,
    const float* __restrict__ dinv, int* __restrict__ csr_src, float* __restrict__ csr_norm) {
  int e = blockIdx.x * 256 + threadIdx.x;
  if (e >= NE) return;
  int d = dstr[e];
  int s = srcr[e];
  int pos = rowptr[d] + atomicAdd(&cursor[d], 1);
  csr_src[pos] = s;
  csr_norm[pos] = dinv[s] * ew[e] * dinv[d];
}

// ---------------- GEMM: xw = A(392960,128) @ Wp(128,64), store cols 0..51 ----
// 256-row tile/block (1535 blocks exact), 256 threads, micro-tile 8x8
// (acc=64 VGPRs, 2.0 LDS-FLOP/byte). K chunked by 32. LDS 45KB -> 3 blocks/CU.
// A-tile stride 36: compute reads (4*rg+k4)%32 conflict-free; staging 2-way (free).
__global__ __launch_bounds__(256, 3) void gemm_kernel(const float* __restrict__ A,
    const float* __restrict__ W, float* __restrict__ out) {
  __shared__ float As[256 * 36];   // 36864 B
  __shared__ float Ws[32 * 64];    // 8192 B
  int tid = threadIdx.x;
  int row0 = blockIdx.x * 256;
  int rg = tid >> 3;        // 0..31 : rows rg + 32*i
  int cg = tid & 7;         // cols cg*8 .. cg*8+7
  int c0 = cg * 8;
  float acc[8][8];
#pragma unroll
  for (int i = 0; i < 8; ++i)
#pragma unroll
    for (int j = 0; j < 8; ++j) acc[i][j] = 0.f;

  for (int kc = 0; kc < 4; ++kc) {
    // stage A chunk: 256 rows x 32 k (8 float4 / thread)
#pragma unroll
    for (int j = 0; j < 8; ++j) {
      int f = tid + 256 * j;        // 0..2047
      int r = f >> 3, kq = f & 7;
      float4 v = *(const float4*)&A[(size_t)(row0 + r) * NF + kc * 32 + kq * 4];
      *(float4*)&As[r * 36 + kq * 4] = v;
    }
    // stage W chunk: 32 k x 64 cols (2 float4 / thread)
#pragma unroll
    for (int j = 0; j < 2; ++j) {
      int f = tid + 256 * j;        // 0..511
      int kk = f >> 4, cq = f & 15;
      *(float4*)&Ws[kk * 64 + cq * 4] = *(const float4*)&W[(size_t)(kc * 32 + kk) * 64 + cq * 4];
    }
    __syncthreads();
#pragma unroll 2
    for (int k4 = 0; k4 < 32; k4 += 4) {
      float4 a[8];
#pragma unroll
      for (int i = 0; i < 8; ++i) a[i] = *(const float4*)&As[(rg + 32 * i) * 36 + k4];
#pragma unroll
      for (int m = 0; m < 4; ++m) {
        float4 w0 = *(const float4*)&Ws[(k4 + m) * 64 + c0];
        float4 w1 = *(const float4*)&Ws[(k4 + m) * 64 + c0 + 4];
#pragma unroll
        for (int i = 0; i < 8; ++i) {
          float av = (m == 0) ? a[i].x : (m == 1) ? a[i].y : (m == 2) ? a[i].z : a[i].w;
          acc[i][0] += av * w0.x; acc[i][1] += av * w0.y;
          acc[i][2] += av * w0.z; acc[i][3] += av * w0.w;
          acc[i][4] += av * w1.x; acc[i][5] += av * w1.y;
          acc[i][6] += av * w1.z; acc[i][7] += av * w1.w;
        }
      }
    }
    __syncthreads();
  }
#pragma unroll
  for (int i = 0; i < 8; ++i) {
    size_t r = row0 + rg + 32 * i;
    if (c0 < NC)                 // cg<=6: cols c0..c0+3 valid (cg==6 -> 48..51)
      *(float4*)&out[r * NC + c0] = make_float4(acc[i][0], acc[i][1], acc[i][2], acc[i][3]);
    if (c0 + 4 < NC)             // cg<=5: cols c0+4..c0+7 valid
      *(float4*)&out[r * NC + c0 + 4] = make_float4(acc[i][4], acc[i][5], acc[i][6], acc[i][7]);
  }
}

// ---------------- GCN aggregation: atomic-free CSR gather (52-col) ----------
// Block = 16 nodes x 13 float4-feats (f4<13 active of 16). Best measured
// version (R1): 1 batch/block; LDS-staged variant (R4) lost 2x to LDS bank
// conflicts (1.7e7) + 1-block/CU occupancy -> L2 random-line reads win.
// XCD-aware decode: xcd = bid&7, pos = bid>>3 gives each XCD a contiguous
// 3072-work range = 16 whole batches; per-batch 638 KB xw slice stays in one
// XCD's L2 (fetched once from HBM instead of 8x).
__global__ __launch_bounds__(256) void gather_kernel(const float4* __restrict__ xw,
    const int* __restrict__ rowptr, const int* __restrict__ csr_src, const float* __restrict__ csr_norm,
    const float* __restrict__ selfn, const float* __restrict__ bp, float4* __restrict__ outg) {
  __shared__ int s_src[GCAP];
  __shared__ float s_nrm[GCAP];
  int bid = blockIdx.x;
  int xcd = bid & 7;
  int pos = bid >> 3;
  int work = xcd * GPX + pos;        // bijective: GWG % 8 == 0
  int b = work / NBLK;               // batch: 16 consecutive batches per XCD
  int nblk = work - b * NBLK;        // node-block within batch
  int tid = threadIdx.x;
  int f4 = tid & 15, nl = tid >> 4;
  int nb = nblk * 16;
  int nend = nb + 16 < NN ? nb + 16 : NN;
  int be0 = rowptr[nb], be1 = rowptr[nend];
  int cnt = be1 - be0;
  int scnt = cnt < GCAP ? cnt : GCAP;
  for (int i = tid; i < scnt; i += 256) {
    s_src[i] = csr_src[be0 + i];
    s_nrm[i] = csr_norm[be0 + i];
  }
  __syncthreads();
  int n = nb + nl;
  if (n >= NN || f4 >= 13) return;
  const float4* xb = xw + (size_t)b * NN * 13;
  float sn = selfn[n];
  float4 v = xb[n * 13 + f4];
  float ax = v.x * sn, ay = v.y * sn, az = v.z * sn, aw = v.w * sn;
  float bx = 0.f, by = 0.f, bz = 0.f, bw = 0.f;
  int le0 = rowptr[n] - be0, le1 = rowptr[n + 1] - be0;
  int lim = le1 < GCAP ? le1 : GCAP;
  int e = le0;
  for (; e + 1 < lim; e += 2) {
    int s1 = s_src[e], s2 = s_src[e + 1];
    float w1 = s_nrm[e], w2 = s_nrm[e + 1];
    float4 u1 = xb[s1 * 13 + f4];
    float4 u2 = xb[s2 * 13 + f4];
    ax += w1 * u1.x; ay += w1 * u1.y; az += w1 * u1.z; aw += w1 * u1.w;
    bx += w2 * u2.x; by += w2 * u2.y; bz += w2 * u2.z; bw += w2 * u2.w;
  }
  if (e < lim) {
    int s1 = s_src[e];
    float w1 = s_nrm[e];
    float4 u1 = xb[s1 * 13 + f4];
    ax += w1 * u1.x; ay += w1 * u1.y; az += w1 * u1.z; aw += w1 * u1.w;
  }
  for (e = (le0 > GCAP ? le0 : GCAP); e < le1; ++e) {   // overflow tail
    int s1 = csr_src[be0 + e];
    float w1 = csr_norm[be0 + e];
    float4 u1 = xb[s1 * 13 + f4];
    ax += w1 * u1.x; ay += w1 * u1.y; az += w1 * u1.z; aw += w1 * u1.w;
  }
  float4 bb = ((const float4*)bp)[f4];
  float4 o = make_float4(ax + bx + bb.x, ay + by + bb.y, az + bz + bb.z, aw + bw + bb.w);
  outg[((size_t)b * NN + n) * 13 + f4] = o;
}

// ---------------- RNN: h = tanh(pre + W_hh h), input term pre-folded --------
// WAVE-AUTONOMOUS: 1 wave = 1 node (50 of 64 lanes active), h lives in a
// wave-private 64-float LDS row. The per-wave DS pipe is in-order, so step
// t's ds_write is seen by step t+1's broadcast reads with NO barrier and NO
// compiler-emitted vmcnt(0) drain (which __syncthreads forced every step in
// the 5-node/block version, stalling on the out-store + xpre prefetch).
// FMA ordering per lane identical to the previous version -> same rounding.
__global__ __launch_bounds__(256, 3) void rnn_kernel(const float* __restrict__ pre,
    const float* __restrict__ Whh, const float* __restrict__ h0, float* __restrict__ out) {
  __shared__ float hs[4 * 64];   // 4 waves x 64-float row (256 B aligned)
  int tid = threadIdx.x;
  int w = tid >> 6;              // wave -> node slot
  int j = tid & 63;
  int n = blockIdx.x * 4 + w;
  if (n >= NN) return;           // wave-uniform exit; no barriers anywhere
  bool active = j < NH;
  int jj = active ? j : 0;
  float2 whh2[25];
  const float2* whhp = (const float2*)(Whh + jj * NH);
#pragma unroll
  for (int q = 0; q < 25; ++q) whh2[q] = whhp[q];
  hs[w * 64 + j] = active ? h0[(size_t)n * NH + j] : 0.f;
  const size_t NPRE = (size_t)NN * NC;
  const size_t NOUT = (size_t)NN * NH;
  const float* prep = pre + (size_t)n * NC + jj;
  float xpre = prep[0];
  const float4* hr = (const float4*)&hs[w * 64];
  for (int t = 0; t < NB; ++t) {
    float a0 = xpre, a1 = 0.f, a2 = 0.f, a3 = 0.f;
    if (t + 1 < NB) xpre = prep[(size_t)(t + 1) * NPRE];  // prefetch next step
#pragma unroll
    for (int q = 0; q < 12; q += 4) {
      float4 h0v = hr[q], h1v = hr[q + 1], h2v = hr[q + 2], h3v = hr[q + 3];
      a0 += h0v.x * whh2[2*q].x   + h0v.y * whh2[2*q].y   + h0v.z * whh2[2*q+1].x + h0v.w * whh2[2*q+1].y;
      a1 += h1v.x * whh2[2*q+2].x + h1v.y * whh2[2*q+2].y + h1v.z * whh2[2*q+3].x + h1v.w * whh2[2*q+3].y;
      a2 += h2v.x * whh2[2*q+4].x + h2v.y * whh2[2*q+4].y + h2v.z * whh2[2*q+5].x + h2v.w * whh2[2*q+5].y;
      a3 += h3v.x * whh2[2*q+6].x + h3v.y * whh2[2*q+6].y + h3v.z * whh2[2*q+7].x + h3v.w * whh2[2*q+7].y;
    }
    {
      float2 ht = *(const float2*)&hs[w * 64 + 48];
      a0 += ht.x * whh2[24].x + ht.y * whh2[24].y;
    }
    float v = (a0 + a1) + (a2 + a3);
    float e = __expf(-2.f * fabsf(v));
    float r = (1.f - e) * __builtin_amdgcn_rcpf(1.f + e);
    float hnew = (v < 0.f) ? -r : r;
    if (active) {
      hs[w * 64 + j] = hnew;     // in-order DS pipe: visible to next-iter reads
      out[(size_t)t * NOUT + (size_t)n * NH + j] = hnew;  // 200 B/wave contiguous
    }
  }
}

// ---------------- host ----------------

extern "C" void kernel_launch(void* const* d_in, const int* in_sizes, int n_in,
                              void* d_out, int out_size, void* d_ws, size_t ws_size,
                              hipStream_t stream) {
  const float* x_in = (const float*)d_in[0];
  const int* ei     = (const int*)d_in[1];
  const float* ew   = (const float*)d_in[2];
  const float* W    = (const float*)d_in[3];
  const float* bias = (const float*)d_in[4];
  const float* Wih  = (const float*)d_in[5];
  const float* Whh  = (const float*)d_in[6];
  const float* bih  = (const float*)d_in[7];
  const float* bhh  = (const float*)d_in[8];
  const float* h0   = (const float*)d_in[9];
  float* out = (float*)d_out;

  char* ws = (char*)d_ws;
  size_t off = 0;
  auto alloc = [&](size_t bytes) {
    size_t o = off;
    off += (bytes + 255) & ~(size_t)255;
    return o;
  };
  float* xw    = (float*)(ws + alloc((size_t)MTOT * NC * 4));         // 81.7 MB
  float* gcn   = (float*)(ws + alloc((size_t)MTOT * NC * 4));         // 81.7 MB
  int*   zb    = (int*)(ws + alloc((size_t)4 * NN * 4));              // zeroed each call
  int* mark = zb;
  int* degc = zb + NN;
  float* degw = (float*)(zb + 2 * NN);
  int* cursor = zb + 3 * NN;
  int*   ranks  = (int*)(ws + alloc(NN * 4));
  int*   srcr   = (int*)(ws + alloc(NE * 4));
  int*   dstr   = (int*)(ws + alloc(NE * 4));
  float* dinv   = (float*)(ws + alloc(NN * 4));
  float* selfn  = (float*)(ws + alloc(NN * 4));
  int*   rowptr = (int*)(ws + alloc((NN + 1) * 4));
  int*   csrc   = (int*)(ws + alloc(NE * 4));
  float* cnorm  = (float*)(ws + alloc(NE * 4));
  float* Wp     = (float*)(ws + alloc(128 * 64 * 4));
  float* bp     = (float*)(ws + alloc(NC * 4));

  init_kernel<<<80, 256, 0, stream>>>(zb, W, Wih, bias, bih, bhh, Wp, bp);
  mark_kernel<<<(2 * NE + 255) / 256, 256, 0, stream>>>(ei, mark);
  exscan_kernel<<<1, 1024, 0, stream>>>(mark, ranks, NN, 0, 0, degw, dinv, selfn);
  remap_deg_kernel<<<(NE + 255) / 256, 256, 0, stream>>>(ei, ew, ranks, srcr, dstr, degc, degw);
  exscan_kernel<<<1, 1024, 0, stream>>>(degc, rowptr, NN, 1, 1, degw, dinv, selfn);
  csr_fill_kernel<<<(NE + 255) / 256, 256, 0, stream>>>(ew, srcr, dstr, rowptr, cursor, dinv, csrc, cnorm);

  gemm_kernel<<<MTOT / 256, 256, 0, stream>>>(x_in, Wp, xw);
  gather_kernel<<<GWG, 256, 0, stream>>>(
      (const float4*)xw, rowptr, csrc, cnorm, selfn, bp, (float4*)gcn);
  rnn_kernel<<<(NN + 3) / 4, 256, 0, stream>>>(gcn, Whh, h0, out);
}